// Round 1
// 777.318 us; speedup vs baseline: 1.0997x; 1.0997x over previous
//
#include <hip/hip_runtime.h>
#include <math.h>

constexpr int Bb = 4, Nn = 2048, Dd = 2048, Ee = 8, Cbn = 512;
constexpr int Mm = Bb * Nn;          // 8192 tokens

typedef _Float16 half8 __attribute__((ext_vector_type(8)));
typedef float floatx16 __attribute__((ext_vector_type(16)));

#define GLL16(g, l)                                                     \
  __builtin_amdgcn_global_load_lds(                                     \
      (const __attribute__((address_space(1))) void*)(g),               \
      (__attribute__((address_space(3))) void*)(l), 16, 0, 0)

#define MFMA_F16(a, b, c) __builtin_amdgcn_mfma_f32_32x32x16_f16(a, b, c, 0, 0, 0)

// Tiled operand layout (both A and B sides), 16 KB per (tile, ktile):
//   [tile][ktile][hl(2)][chunk(4)][row(128)][8 halves]
// k within ktile = chunk*8 + j. Linear GLL16 copy of one tile-slab gives an
// LDS image where a 32x32x16 f16 fragment read (row = base+(lane&31),
// chunk = s*2 + (lane>>5)) is two contiguous 512B runs -> conflict-free.

// ---------------- transpose + split W: [E,D,C] f32 -> tiled hi/lo f16 -------
__global__ __launch_bounds__(256) void transpose_w(const float* __restrict__ W,
                                                   _Float16* __restrict__ WT) {
  const int kt = blockIdx.x;  // 0..31, 64 d's each
  const int ct = blockIdx.y;  // 0..7, 64 c's each
  const int e = blockIdx.z;   // 0..7
  __shared__ _Float16 thi[64][72];  // [c][d]; 72*2=144B stride keeps 16B align
  __shared__ _Float16 tlo[64][72];
  const int tx = threadIdx.x & 15, ty = threadIdx.x >> 4;
  const float* src = W + ((size_t)(e * 2048 + kt * 64)) * 512 + ct * 64;
#pragma unroll
  for (int p = 0; p < 4; ++p) {
    int kk = ty + p * 16;
    float4 v = *(const float4*)(src + (size_t)kk * 512 + tx * 4);
    _Float16 hh;
    hh = (_Float16)v.x; thi[tx * 4 + 0][kk] = hh; tlo[tx * 4 + 0][kk] = (_Float16)(v.x - (float)hh);
    hh = (_Float16)v.y; thi[tx * 4 + 1][kk] = hh; tlo[tx * 4 + 1][kk] = (_Float16)(v.y - (float)hh);
    hh = (_Float16)v.z; thi[tx * 4 + 2][kk] = hh; tlo[tx * 4 + 2][kk] = (_Float16)(v.z - (float)hh);
    hh = (_Float16)v.w; thi[tx * 4 + 3][kk] = hh; tlo[tx * 4 + 3][kk] = (_Float16)(v.w - (float)hh);
  }
  __syncthreads();
  const int ntile = e * 4 + (ct >> 1);
#pragma unroll
  for (int p = 0; p < 2; ++p) {
    int unit = threadIdx.x + p * 256;  // 0..511
    int ch = unit >> 6;                // 0..7 (8 d's each)
    int cc = unit & 63;
    int ktile = kt * 2 + (ch >> 2);
    int chunk = ch & 3;
    int row = (ct & 1) * 64 + cc;
    _Float16* dst = WT + ((size_t)(ntile * 64 + ktile)) * 8192 + chunk * 1024 + row * 8;
    *(half8*)dst = *(const half8*)(&thi[cc][ch * 8]);
    *(half8*)(dst + 4096) = *(const half8*)(&tlo[cc][ch * 8]);
  }
}

// ---------------- pre-split X: [M,D] f32 -> tiled hi/lo f16 ------------------
__global__ __launch_bounds__(256) void split_x(const float* __restrict__ X,
                                               _Float16* __restrict__ XT) {
  const int mt = blockIdx.x;  // 0..63
  const int kt = blockIdx.y;  // 0..63
  const int tid = threadIdx.x;
  _Float16* tb = XT + ((size_t)(mt * 64 + kt)) * 8192;
#pragma unroll
  for (int p = 0; p < 2; ++p) {
    const int u = tid + p * 256;  // 0..511
    const int chunk = u & 3;
    const int row = u >> 2;
    const float* src = X + ((size_t)(mt * 128 + row)) * 2048 + kt * 32 + chunk * 8;
    float4 a = *(const float4*)src;
    float4 b = *(const float4*)(src + 4);
    float f[8] = {a.x, a.y, a.z, a.w, b.x, b.y, b.z, b.w};
    half8 hi, lo;
#pragma unroll
    for (int j = 0; j < 8; ++j) {
      _Float16 hh = (_Float16)f[j];
      hi[j] = hh;
      lo[j] = (_Float16)(f[j] - (float)hh);
    }
    *(half8*)(tb + chunk * 1024 + row * 8) = hi;
    *(half8*)(tb + 4096 + chunk * 1024 + row * 8) = lo;
  }
}

// ---------------- MFMA GEMM: all-f16 operands, dbuf LDS, 1 barrier/ktile ----
__global__ __launch_bounds__(256) void gemm_mfma(const _Float16* __restrict__ XT,
                                                 const _Float16* __restrict__ WT,
                                                 float* __restrict__ partial) {
  // 16x16 supertile swizzle for L2 locality
  const int bid = blockIdx.x;
  const int st = bid >> 8;
  const int stm = st & 3;
  const int stn = st >> 2;
  const int li = bid & 255;
  const int mtile = stm * 16 + (li >> 4);   // 0..63
  const int ntile = stn * 16 + (li & 15);   // 0..31

  const int tid = threadIdx.x;
  const int wave = tid >> 6, lane = tid & 63;
  const int wm = wave >> 1, wn = wave & 1;
  const int h = lane >> 5;

  // double buffer: [buf(2)][A 16KB | B 16KB]
  __shared__ __align__(16) char lds[65536];

  const char* aSrc = (const char*)XT + (size_t)mtile * 64 * 16384 + wave * 4096 + lane * 16;
  const char* bSrc = (const char*)WT + (size_t)ntile * 64 * 16384 + wave * 4096 + lane * 16;

  const int rowA0 = wm * 64 + (lane & 31);
  const int rB0 = wn * 64 + (lane & 31);

  int aOff[2][2], bOff[2][2];  // [s][hl], row1 at +512
#pragma unroll
  for (int s = 0; s < 2; ++s)
#pragma unroll
    for (int hl = 0; hl < 2; ++hl) {
      aOff[s][hl] = hl * 8192 + (s * 2 + h) * 2048 + rowA0 * 16;
      bOff[s][hl] = 16384 + hl * 8192 + (s * 2 + h) * 2048 + rB0 * 16;
    }

  floatx16 acc00 = {}, acc01 = {}, acc10 = {}, acc11 = {};

  // prologue: stage ktile 0 into buf0
#pragma unroll
  for (int q = 0; q < 4; ++q) {
    GLL16(aSrc + q * 1024, lds + wave * 4096 + q * 1024);
    GLL16(bSrc + q * 1024, lds + 16384 + wave * 4096 + q * 1024);
  }
  __syncthreads();  // implicit vmcnt(0) drain

  for (int kt = 0; kt < 64; ++kt) {
    const int cur = kt & 1;
    if (kt < 63) {
      // issue next-tile prefetch BEFORE compute; latency hides under MFMAs
      const char* a = aSrc + (size_t)(kt + 1) * 16384;
      const char* b = bSrc + (size_t)(kt + 1) * 16384;
      char* base = lds + (cur ^ 1) * 32768 + wave * 4096;
#pragma unroll
      for (int q = 0; q < 4; ++q) {
        GLL16(a + q * 1024, base + q * 1024);
        GLL16(b + q * 1024, base + 16384 + q * 1024);
      }
    }
    const char* L = lds + cur * 32768;
#pragma unroll
    for (int s = 0; s < 2; ++s) {
      half8 ah0 = *(const half8*)(L + aOff[s][0]);
      half8 ah1 = *(const half8*)(L + aOff[s][0] + 512);
      half8 al0 = *(const half8*)(L + aOff[s][1]);
      half8 al1 = *(const half8*)(L + aOff[s][1] + 512);
      half8 bh0 = *(const half8*)(L + bOff[s][0]);
      half8 bh1 = *(const half8*)(L + bOff[s][0] + 512);
      half8 bl0 = *(const half8*)(L + bOff[s][1]);
      half8 bl1 = *(const half8*)(L + bOff[s][1] + 512);
      acc00 = MFMA_F16(ah0, bh0, acc00);
      acc00 = MFMA_F16(ah0, bl0, acc00);
      acc00 = MFMA_F16(al0, bh0, acc00);
      acc01 = MFMA_F16(ah0, bh1, acc01);
      acc01 = MFMA_F16(ah0, bl1, acc01);
      acc01 = MFMA_F16(al0, bh1, acc01);
      acc10 = MFMA_F16(ah1, bh0, acc10);
      acc10 = MFMA_F16(ah1, bl0, acc10);
      acc10 = MFMA_F16(al1, bh0, acc10);
      acc11 = MFMA_F16(ah1, bh1, acc11);
      acc11 = MFMA_F16(ah1, bl1, acc11);
      acc11 = MFMA_F16(al1, bh1, acc11);
    }
    __syncthreads();  // one barrier/ktile: reads of cur done, prefetch drained
  }

  // epilogue: per-row sum of squares over this wave's 64 cols
  float myv = 0.f;
#pragma unroll
  for (int i = 0; i < 2; ++i) {
    const floatx16& c0 = i ? acc10 : acc00;
    const floatx16& c1 = i ? acc11 : acc01;
#pragma unroll
    for (int reg = 0; reg < 16; ++reg) {
      float v = c0[reg] * c0[reg] + c1[reg] * c1[reg];
#pragma unroll
      for (int m = 1; m <= 16; m <<= 1) v += __shfl_xor(v, m, 64);
      if ((lane & 31) == i * 16 + reg) myv = v;
    }
  }
  {
    const int i = (lane & 31) >> 4;
    const int reg = lane & 15;
    const int row = i * 32 + (reg & 3) + 8 * (reg >> 2) + 4 * h;
    const int token = mtile * 128 + wm * 64 + row;
    const int slice = ntile * 2 + wn;  // e*8+u
    partial[(size_t)token * 64 + slice] = myv;
  }
}

// ---------------- softmax + top-2 per token ---------------------------------
__global__ void route_kernel(const float* __restrict__ partial,
                             int* __restrict__ idx1, int* __restrict__ idx2,
                             float* __restrict__ p1, float* __restrict__ p2) {
  int t = blockIdx.x * blockDim.x + threadIdx.x;
  if (t >= Mm) return;
  float l[Ee];
  float mx = -1e30f;
#pragma unroll
  for (int e = 0; e < Ee; ++e) {
    float s = 0.f;
#pragma unroll
    for (int u = 0; u < 8; ++u) s += partial[(size_t)t * 64 + e * 8 + u];
    l[e] = sqrtf(s);
    mx = fmaxf(mx, l[e]);
  }
  float p[Ee];
  float s = 0.f;
#pragma unroll
  for (int e = 0; e < Ee; ++e) {
    p[e] = expf(l[e] - mx);
    s += p[e];
  }
  float inv = 1.f / s;
  int i1 = 0;
  float b1 = l[0];
#pragma unroll
  for (int e = 1; e < Ee; ++e)
    if (l[e] > b1) { b1 = l[e]; i1 = e; }
  int i2 = -1;
  float b2 = -1e30f;
#pragma unroll
  for (int e = 0; e < Ee; ++e)
    if (e != i1 && l[e] > b2) { b2 = l[e]; i2 = e; }
  idx1[t] = i1;
  idx2[t] = i2;
  p1[t] = p[i1] * inv;
  p2[t] = p[i2] * inv;
}

// ---------------- per-batch capacity priority scan --------------------------
__global__ void scan_kernel(const int* __restrict__ idx1,
                            const int* __restrict__ idx2,
                            int* __restrict__ prios) {
  const int b = blockIdx.x;
  const int tid = threadIdx.x;
  __shared__ int cnts[256][8];
  int cnt[8] = {0, 0, 0, 0, 0, 0, 0, 0};
  int eloc[16];
  const int base_p = tid * 16;
#pragma unroll
  for (int i = 0; i < 16; ++i) {
    int p = base_p + i;
    int k = p >> 11;
    int n = p & (Nn - 1);
    int e = (k == 0 ? idx1 : idx2)[b * Nn + n];
    eloc[i] = e;
    cnt[e]++;
  }
#pragma unroll
  for (int e = 0; e < 8; ++e) cnts[tid][e] = cnt[e];
  __syncthreads();
  if (tid < 8) {
    int run = 0;
    for (int i = 0; i < 256; ++i) {
      int v = cnts[i][tid];
      cnts[i][tid] = run;
      run += v;
    }
  }
  __syncthreads();
  int base[8];
#pragma unroll
  for (int e = 0; e < 8; ++e) base[e] = cnts[tid][e];
#pragma unroll
  for (int i = 0; i < 16; ++i) {
    int e = eloc[i];
    prios[b * 2 * Nn + base_p + i] = base[e]++;
  }
}

// ---------------- fused zero + scatter (one block per token) ----------------
__global__ __launch_bounds__(256) void zscatter_kernel(const int* __restrict__ idx1,
                                                       const int* __restrict__ idx2,
                                                       const float* __restrict__ p1,
                                                       const float* __restrict__ p2,
                                                       const int* __restrict__ prios,
                                                       float* __restrict__ out, int cap) {
  const int t = blockIdx.x;       // token 0..Mm-1
  const int ec = Ee * cap;
  float4* o1 = (float4*)(out + (size_t)t * ec);             // dispatch slice
  float4* o2 = (float4*)(out + (size_t)(Mm + t) * ec);      // combine slice
  const float4 z = make_float4(0.f, 0.f, 0.f, 0.f);
  const int n4 = ec / 4;
  for (int i = threadIdx.x; i < n4; i += 256) {
    o1[i] = z;
    o2[i] = z;
  }
  __syncthreads();
  if (threadIdx.x == 0) {
    const int b = t >> 11;
    const int n = t & (Nn - 1);
    int e = idx1[t];
    int p = prios[b * 2 * Nn + n];
    if (p < cap) {
      out[(size_t)t * ec + e * cap + p] = 1.f;
      out[(size_t)(Mm + t) * ec + e * cap + p] = p1[t];
    }
    e = idx2[t];
    p = prios[b * 2 * Nn + Nn + n];
    if (p < cap) {
      out[(size_t)t * ec + e * cap + p] = 1.f;
      out[(size_t)(Mm + t) * ec + e * cap + p] = p2[t];
    }
  }
}

extern "C" void kernel_launch(void* const* d_in, const int* in_sizes, int n_in,
                              void* d_out, int out_size, void* d_ws, size_t ws_size,
                              hipStream_t stream) {
  const float* X = (const float*)d_in[0];
  const float* W = (const float*)d_in[1];
  float* out = (float*)d_out;
  const int cap = out_size / (2 * Bb * Nn * Ee);  // 640

  char* ws = (char*)d_ws;
  _Float16* WT = (_Float16*)ws;                    // 32 MB tiled hi/lo W^T
  float* partial = (float*)(ws + 33554432ull);     // Mm*64 f32 = 2 MB
  int* idx1 = (int*)(ws + 35651584ull);
  int* idx2 = idx1 + Mm;
  float* p1 = (float*)(idx2 + Mm);
  float* p2 = p1 + Mm;
  int* prios = (int*)(p2 + Mm);

  // XT (64 MB, tiled hi/lo X) lives in d_out as scratch: it is consumed by
  // gemm_mfma and then fully overwritten by zscatter_kernel (stream-ordered).
  _Float16* XT = (_Float16*)d_out;

  transpose_w<<<dim3(32, 8, 8), 256, 0, stream>>>(W, WT);
  split_x<<<dim3(64, 64), 256, 0, stream>>>(X, XT);
  gemm_mfma<<<2048, 256, 0, stream>>>(XT, WT, partial);
  route_kernel<<<Mm / 256, 256, 0, stream>>>(partial, idx1, idx2, p1, p2);
  scan_kernel<<<Bb, 256, 0, stream>>>(idx1, idx2, prios);
  zscatter_kernel<<<Mm, 256, 0, stream>>>(idx1, idx2, p1, p2, prios, out, cap);
}

// Round 3
// 757.480 us; speedup vs baseline: 1.1285x; 1.0262x over previous
//
#include <hip/hip_runtime.h>
#include <math.h>

constexpr int Bb = 4, Nn = 2048, Dd = 2048, Ee = 8, Cbn = 512;
constexpr int Mm = Bb * Nn;          // 8192 tokens

typedef _Float16 half8 __attribute__((ext_vector_type(8)));
typedef float floatx16 __attribute__((ext_vector_type(16)));

#define GLL16(g, l)                                                     \
  __builtin_amdgcn_global_load_lds(                                     \
      (const __attribute__((address_space(1))) void*)(g),               \
      (__attribute__((address_space(3))) void*)(l), 16, 0, 0)

#define MFMA_F16(a, b, c) __builtin_amdgcn_mfma_f32_32x32x16_f16(a, b, c, 0, 0, 0)

// Operand layout (A and B sides), 8 KB per (128-tile, kt16):
//   [tile128][kt16(128)][hl(2)][chunk(2)][row(128)][8 f16]
// k within kt16 = chunk*8 + j -> matches mfma A/B lane layout (k = (lane>>5)*8+j).
// Linear GLL16 copy of one slab gives conflict-free ds_read_b128 fragments
// (32 consecutive rows x 16B = contiguous 512B per half-wave).

// ---------------- transpose + split W: [E,D,C] f32 -> tiled hi/lo f16 -------
__global__ __launch_bounds__(256) void transpose_w(const float* __restrict__ W,
                                                   _Float16* __restrict__ WT) {
  const int kt = blockIdx.x;  // 0..31, 64 d's each
  const int ct = blockIdx.y;  // 0..7, 64 c's each
  const int e = blockIdx.z;   // 0..7
  __shared__ _Float16 thi[64][72];  // [c][d]
  __shared__ _Float16 tlo[64][72];
  const int tx = threadIdx.x & 15, ty = threadIdx.x >> 4;
  const float* src = W + ((size_t)(e * 2048 + kt * 64)) * 512 + ct * 64;
#pragma unroll
  for (int p = 0; p < 4; ++p) {
    int kk = ty + p * 16;
    float4 v = *(const float4*)(src + (size_t)kk * 512 + tx * 4);
    _Float16 hh;
    hh = (_Float16)v.x; thi[tx * 4 + 0][kk] = hh; tlo[tx * 4 + 0][kk] = (_Float16)(v.x - (float)hh);
    hh = (_Float16)v.y; thi[tx * 4 + 1][kk] = hh; tlo[tx * 4 + 1][kk] = (_Float16)(v.y - (float)hh);
    hh = (_Float16)v.z; thi[tx * 4 + 2][kk] = hh; tlo[tx * 4 + 2][kk] = (_Float16)(v.z - (float)hh);
    hh = (_Float16)v.w; thi[tx * 4 + 3][kk] = hh; tlo[tx * 4 + 3][kk] = (_Float16)(v.w - (float)hh);
  }
  __syncthreads();
  const int nt = e * 4 + (ct >> 1);  // 128-col tile index, 0..31
#pragma unroll
  for (int p = 0; p < 2; ++p) {
    int unit = threadIdx.x + p * 256;  // 0..511
    int ch = unit >> 6;                // 0..7 (8 d's each)
    int cc = unit & 63;
    int kt16 = kt * 4 + (ch >> 1);
    int chunk = ch & 1;
    int row = (ct & 1) * 64 + cc;
    _Float16* dst = WT + ((size_t)(nt * 128 + kt16)) * 4096 + chunk * 1024 + row * 8;
    *(half8*)dst = *(const half8*)(&thi[cc][ch * 8]);
    *(half8*)(dst + 2048) = *(const half8*)(&tlo[cc][ch * 8]);
  }
}

// ---------------- pre-split X: [M,D] f32 -> tiled hi/lo f16 ------------------
__global__ __launch_bounds__(256) void split_x(const float* __restrict__ X,
                                               _Float16* __restrict__ XT) {
  const int mt = blockIdx.x;  // 0..63 (128-row tile)
  const int kb = blockIdx.y;  // 0..63 (32-k block)
  const int tid = threadIdx.x;
#pragma unroll
  for (int p = 0; p < 2; ++p) {
    const int u = tid + p * 256;  // 0..511
    const int c4 = u & 3;
    const int row = u >> 2;
    const float* src = X + ((size_t)(mt * 128 + row)) * 2048 + kb * 32 + c4 * 8;
    float4 a = *(const float4*)src;
    float4 b = *(const float4*)(src + 4);
    float f[8] = {a.x, a.y, a.z, a.w, b.x, b.y, b.z, b.w};
    half8 hi, lo;
#pragma unroll
    for (int j = 0; j < 8; ++j) {
      _Float16 hh = (_Float16)f[j];
      hi[j] = hh;
      lo[j] = (_Float16)(f[j] - (float)hh);
    }
    const int kt16 = kb * 2 + (c4 >> 1);
    const int chunk = c4 & 1;
    _Float16* dst = XT + ((size_t)(mt * 128 + kt16)) * 4096 + chunk * 1024 + row * 8;
    *(half8*)dst = hi;
    *(half8*)(dst + 2048) = lo;
  }
}

// ---------------- MFMA GEMM: 256x256 tile, 8 waves, ring-4 counted vmcnt ----
__global__ __launch_bounds__(512) void gemm_mfma(const _Float16* __restrict__ XT,
                                                 const _Float16* __restrict__ WT,
                                                 float* __restrict__ partial) {
  // XCD-aware swizzle (512 blocks, 512%8==0 -> simple bijection)
  const int bid = blockIdx.x;
  const int swz = (bid & 7) * 64 + (bid >> 3);
  const int bM = swz >> 4;  // 0..31 (256 rows)
  const int bN = swz & 15;  // 0..15 (256 cols)

  const int tid = threadIdx.x;
  const int w = tid >> 6, l = tid & 63;
  const int wm = w >> 2, wn = w & 3;  // wave tile: 128 rows x 64 cols
  const int h = l >> 5, l31 = l & 31;

  // ring of 4 buffers x (A 16KB | B 16KB) = 128 KB
  __shared__ __align__(16) char lds[131072];

  // ---- staging: 4 GLL16/wave/ktile (2 A + 2 B); LDS image = linear slab copy
  const char* XTb = (const char*)XT;
  const char* WTb = (const char*)WT;
  const char* srcA[2];
  const char* srcB[2];
  int ldsAo[2], ldsBo[2];
#pragma unroll
  for (int q = 0; q < 2; ++q) {
    const int i3 = q * 4 + (w >> 1);  // [half-tile][hl][chunk]
    srcA[q] = XTb + ((size_t)((bM * 2 + (i3 >> 2)) * 128)) * 8192 +
              (i3 & 3) * 2048 + (w & 1) * 1024 + l * 16;
    srcB[q] = WTb + ((size_t)((bN * 2 + (i3 >> 2)) * 128)) * 8192 +
              (i3 & 3) * 2048 + (w & 1) * 1024 + l * 16;
    ldsAo[q] = q * 8192 + w * 1024;           // wave-uniform; HW adds lane*16
    ldsBo[q] = 16384 + q * 8192 + w * 1024;
  }

  // ---- fragment read offsets (within a buffer)
  int aoff[4][2], boff[2][2];
#pragma unroll
  for (int mf = 0; mf < 4; ++mf)
#pragma unroll
    for (int hl = 0; hl < 2; ++hl)
      aoff[mf][hl] = wm * 8192 + hl * 4096 + h * 2048 + (mf * 32 + l31) * 16;
#pragma unroll
  for (int nf = 0; nf < 2; ++nf)
#pragma unroll
    for (int hl = 0; hl < 2; ++hl)
      boff[nf][hl] = 16384 + (wn >> 1) * 8192 + hl * 4096 + h * 2048 +
                     ((wn & 1) * 64 + nf * 32 + l31) * 16;

  floatx16 acc[4][2] = {};

  auto stage = [&](int t) {
    const size_t ko = (size_t)t * 8192;
    char* base = lds + (t & 3) * 32768;
#pragma unroll
    for (int q = 0; q < 2; ++q) {
      GLL16(srcA[q] + ko, base + ldsAo[q]);
      GLL16(srcB[q] + ko, base + ldsBo[q]);
    }
  };
  auto compute = [&](int t) {
    const char* Lb = lds + (t & 3) * 32768;
    half8 ah[4], al[4], bh[2], bl[2];
#pragma unroll
    for (int mf = 0; mf < 4; ++mf) {
      ah[mf] = *(const half8*)(Lb + aoff[mf][0]);
      al[mf] = *(const half8*)(Lb + aoff[mf][1]);
    }
#pragma unroll
    for (int nf = 0; nf < 2; ++nf) {
      bh[nf] = *(const half8*)(Lb + boff[nf][0]);
      bl[nf] = *(const half8*)(Lb + boff[nf][1]);
    }
    __builtin_amdgcn_s_setprio(1);
#pragma unroll
    for (int mf = 0; mf < 4; ++mf)
#pragma unroll
      for (int nf = 0; nf < 2; ++nf) {
        acc[mf][nf] = MFMA_F16(ah[mf], bh[nf], acc[mf][nf]);
        acc[mf][nf] = MFMA_F16(ah[mf], bl[nf], acc[mf][nf]);
        acc[mf][nf] = MFMA_F16(al[mf], bh[nf], acc[mf][nf]);
      }
    __builtin_amdgcn_s_setprio(0);
  };

  // ---- prologue: stage ktiles 0..2 into ring slots 0..2
  stage(0);
  stage(1);
  stage(2);
  asm volatile("s_waitcnt vmcnt(8)" ::: "memory");  // slot0's 4 oldest done
  __builtin_amdgcn_s_barrier();

  // ---- steady state: 3 ktiles in flight, never drain to 0
  for (int kt = 0; kt < 125; ++kt) {
    stage(kt + 3);
    compute(kt);
    asm volatile("s_waitcnt vmcnt(8)" ::: "memory");  // ktile kt+1 landed
    __builtin_amdgcn_s_barrier();
  }
  // ---- tail: slots 1,2,3 hold ktiles 125,126,127; no more writes
  asm volatile("s_waitcnt vmcnt(0)" ::: "memory");
  __builtin_amdgcn_s_barrier();
  compute(125);
  compute(126);
  compute(127);

  // ---- epilogue: per-row sum of squares over this wave's 64 cols -----------
  const int slice = bN * 4 + wn;  // n/64 index, 0..63
  float out0 = 0.f, out1 = 0.f;
#pragma unroll
  for (int j = 0; j < 2; ++j) {
    float mv = 0.f;
#pragma unroll
    for (int ii = 0; ii < 2; ++ii) {
      const floatx16& c0 = acc[j * 2 + ii][0];
      const floatx16& c1 = acc[j * 2 + ii][1];
#pragma unroll
      for (int reg = 0; reg < 16; ++reg) {
        float v = c0[reg] * c0[reg] + c1[reg] * c1[reg];
#pragma unroll
        for (int m = 1; m <= 16; m <<= 1) v += __shfl_xor(v, m, 64);
        if (l31 == ii * 16 + reg) mv = v;
      }
    }
    if (j == 0) out0 = mv; else out1 = mv;
  }
  {
    const int reg = l & 15;
    const int ii = l31 >> 4;
    const int rowin = (reg & 3) + 8 * (reg >> 2) + 4 * h;
    const int tok = bM * 256 + wm * 128 + ii * 32 + rowin;
    partial[(size_t)tok * 64 + slice] = out0;
    partial[(size_t)(tok + 64) * 64 + slice] = out1;
  }
}

// ---------------- softmax + top-2 per token ---------------------------------
__global__ void route_kernel(const float* __restrict__ partial,
                             int* __restrict__ idx1, int* __restrict__ idx2,
                             float* __restrict__ p1, float* __restrict__ p2) {
  int t = blockIdx.x * blockDim.x + threadIdx.x;
  if (t >= Mm) return;
  float l[Ee];
  float mx = -1e30f;
#pragma unroll
  for (int e = 0; e < Ee; ++e) {
    float s = 0.f;
#pragma unroll
    for (int u = 0; u < 8; ++u) s += partial[(size_t)t * 64 + e * 8 + u];
    l[e] = sqrtf(s);
    mx = fmaxf(mx, l[e]);
  }
  float p[Ee];
  float s = 0.f;
#pragma unroll
  for (int e = 0; e < Ee; ++e) {
    p[e] = expf(l[e] - mx);
    s += p[e];
  }
  float inv = 1.f / s;
  int i1 = 0;
  float b1 = l[0];
#pragma unroll
  for (int e = 1; e < Ee; ++e)
    if (l[e] > b1) { b1 = l[e]; i1 = e; }
  int i2 = -1;
  float b2 = -1e30f;
#pragma unroll
  for (int e = 0; e < Ee; ++e)
    if (e != i1 && l[e] > b2) { b2 = l[e]; i2 = e; }
  idx1[t] = i1;
  idx2[t] = i2;
  p1[t] = p[i1] * inv;
  p2[t] = p[i2] * inv;
}

// ---------------- per-batch capacity priority scan --------------------------
__global__ void scan_kernel(const int* __restrict__ idx1,
                            const int* __restrict__ idx2,
                            int* __restrict__ prios) {
  const int b = blockIdx.x;
  const int tid = threadIdx.x;
  __shared__ int cnts[256][8];
  int cnt[8] = {0, 0, 0, 0, 0, 0, 0, 0};
  int eloc[16];
  const int base_p = tid * 16;
#pragma unroll
  for (int i = 0; i < 16; ++i) {
    int p = base_p + i;
    int k = p >> 11;
    int n = p & (Nn - 1);
    int e = (k == 0 ? idx1 : idx2)[b * Nn + n];
    eloc[i] = e;
    cnt[e]++;
  }
#pragma unroll
  for (int e = 0; e < 8; ++e) cnts[tid][e] = cnt[e];
  __syncthreads();
  if (tid < 8) {
    int run = 0;
    for (int i = 0; i < 256; ++i) {
      int v = cnts[i][tid];
      cnts[i][tid] = run;
      run += v;
    }
  }
  __syncthreads();
  int base[8];
#pragma unroll
  for (int e = 0; e < 8; ++e) base[e] = cnts[tid][e];
#pragma unroll
  for (int i = 0; i < 16; ++i) {
    int e = eloc[i];
    prios[b * 2 * Nn + base_p + i] = base[e]++;
  }
}

// ---------------- fused zero + scatter (one block per token) ----------------
__global__ __launch_bounds__(256) void zscatter_kernel(const int* __restrict__ idx1,
                                                       const int* __restrict__ idx2,
                                                       const float* __restrict__ p1,
                                                       const float* __restrict__ p2,
                                                       const int* __restrict__ prios,
                                                       float* __restrict__ out, int cap) {
  const int t = blockIdx.x;       // token 0..Mm-1
  const int ec = Ee * cap;
  float4* o1 = (float4*)(out + (size_t)t * ec);             // dispatch slice
  float4* o2 = (float4*)(out + (size_t)(Mm + t) * ec);      // combine slice
  const float4 z = make_float4(0.f, 0.f, 0.f, 0.f);
  const int n4 = ec / 4;
  for (int i = threadIdx.x; i < n4; i += 256) {
    o1[i] = z;
    o2[i] = z;
  }
  __syncthreads();
  if (threadIdx.x == 0) {
    const int b = t >> 11;
    const int n = t & (Nn - 1);
    int e = idx1[t];
    int p = prios[b * 2 * Nn + n];
    if (p < cap) {
      out[(size_t)t * ec + e * cap + p] = 1.f;
      out[(size_t)(Mm + t) * ec + e * cap + p] = p1[t];
    }
    e = idx2[t];
    p = prios[b * 2 * Nn + Nn + n];
    if (p < cap) {
      out[(size_t)t * ec + e * cap + p] = 1.f;
      out[(size_t)(Mm + t) * ec + e * cap + p] = p2[t];
    }
  }
}

extern "C" void kernel_launch(void* const* d_in, const int* in_sizes, int n_in,
                              void* d_out, int out_size, void* d_ws, size_t ws_size,
                              hipStream_t stream) {
  const float* X = (const float*)d_in[0];
  const float* W = (const float*)d_in[1];
  float* out = (float*)d_out;
  const int cap = out_size / (2 * Bb * Nn * Ee);  // 640

  char* ws = (char*)d_ws;
  _Float16* WT = (_Float16*)ws;                    // 32 MB tiled hi/lo W^T
  float* partial = (float*)(ws + 33554432ull);     // Mm*64 f32 = 2 MB
  int* idx1 = (int*)(ws + 35651584ull);
  int* idx2 = idx1 + Mm;
  float* p1 = (float*)(idx2 + Mm);
  float* p2 = p1 + Mm;
  int* prios = (int*)(p2 + Mm);

  // XT (64 MB, tiled hi/lo X) lives in d_out as scratch: consumed by gemm_mfma
  // and then fully overwritten by zscatter_kernel (stream-ordered).
  _Float16* XT = (_Float16*)d_out;

  transpose_w<<<dim3(32, 8, 8), 256, 0, stream>>>(W, WT);
  split_x<<<dim3(64, 64), 256, 0, stream>>>(X, XT);
  gemm_mfma<<<512, 512, 0, stream>>>(XT, WT, partial);
  route_kernel<<<Mm / 256, 256, 0, stream>>>(partial, idx1, idx2, p1, p2);
  scan_kernel<<<Bb, 256, 0, stream>>>(idx1, idx2, prios);
  zscatter_kernel<<<Mm, 256, 0, stream>>>(idx1, idx2, p1, p2, prios, out, cap);
}